// Round 16
// baseline (107.979 us; speedup 1.0000x reference)
//
#include <hip/hip_runtime.h>
#include <hip/hip_bf16.h>

// out[b] = SCALE*query[b]@P[b] + row[b]
//   M  = Wc1^T + prev@Wc2^T            (Mt = M^T, fp32+bf16)
//   Tt[b] = NT(Mt, keyzT[b]) ; W2 = Wq^T@Wk ; u = Wq^T bk ; w3 = Wk^T bq
//   Pt[b] = NT(Tt[b], W2) + s1[b][d2]*u[d0]
//   row[b][d] = bc - 1e9*sm0 + SCALE*(w3@T[b] + (bq.bk)*s1)
// r16: g5_pipe moved to mfma_f32_32x32x16_bf16 (2x FLOP/LDS-byte, half the
// MFMA issue count, 32x32 pipe 15% faster at ubench). Wave grid 4Mx2N,
// per-wave 64x96, acc[2][3] f32x16. A/B frag: row=lane&31, k=(lane>>5)*8+j
// (canonical extension of our verified 16x16x32 mapping); C/D per m74/m101.
// Everything else frozen from r15 (107.7 us best).

typedef __attribute__((ext_vector_type(8))) short short8;
typedef __attribute__((ext_vector_type(4))) float f32x4;
typedef __attribute__((ext_vector_type(16))) float f32x16;

#define SCALE 0.03608439182435161f   /* 1/sqrt(768) */

__device__ inline unsigned short f2bf(float x) {
  unsigned int u = __builtin_bit_cast(unsigned int, x);
  u = (u + 0x7fffu + ((u >> 16) & 1u)) >> 16;   // RNE
  return (unsigned short)u;
}
__device__ inline float bf2f(unsigned short h) {
  return __builtin_bit_cast(float, ((unsigned int)h) << 16);
}

// ---------------- fused prep: grid (12,12,34) ----------------
__global__ void k_prep_all(
    const float* __restrict__ Wq, const float* __restrict__ Wk,
    const float* __restrict__ key, const int* __restrict__ mask,
    const float* __restrict__ prev, const float* __restrict__ Wc,
    const float* __restrict__ query,
    unsigned short* __restrict__ WqT, unsigned short* __restrict__ WkT,
    unsigned short* __restrict__ keyzT, unsigned short* __restrict__ prev_bf,
    unsigned short* __restrict__ Wc2_bf, unsigned short* __restrict__ query_bf)
{
  __shared__ float t[64][65];
  const int z = blockIdx.z;
  const int tid = threadIdx.x;
  if (z < 10) {                       // transpose+cvt
    const float* src;
    unsigned short* dst;
    const int* mb = nullptr;
    if (z == 0) { src = Wq; dst = WqT; }
    else if (z == 1) { src = Wk; dst = WkT; }
    else {
      int b = z - 2;
      src = key + (long long)b * 589824;
      dst = keyzT + (long long)b * 589824;
      mb = mask + b * 768;
    }
    int bx = blockIdx.x * 64, by = blockIdx.y * 64;
    int tx = tid & 63, ty = tid >> 6;
    #pragma unroll
    for (int i = 0; i < 64; i += 4) {
      float v = src[(long long)(by + ty + i) * 768 + bx + tx];
      if (mb) v = mb[by + ty + i] ? v : 0.0f;
      t[ty + i][tx] = v;
    }
    __syncthreads();
    #pragma unroll
    for (int i = 0; i < 64; i += 4)
      dst[(long long)(bx + ty + i) * 768 + by + tx] = f2bf(t[tx][ty + i]);
    return;
  }
  const int r = tid >> 2, c0 = (tid & 3) * 16;
  const float* sr;
  unsigned short* dr;
  if (z == 10) {
    int row = blockIdx.y * 64 + r, col = blockIdx.x * 64 + c0;
    sr = prev + (long long)row * 768 + col;
    dr = prev_bf + (long long)row * 768 + col;
  } else if (z == 11) {
    int row = blockIdx.y * 64 + r, col = blockIdx.x * 64 + c0;
    sr = Wc + (long long)row * 1536 + 768 + col;
    dr = Wc2_bf + (long long)row * 768 + col;
  } else {
    int tz = (z - 12) * 144 + blockIdx.y * 12 + blockIdx.x;
    if (tz >= 3072) return;
    int b = tz / 384, rmn = tz - b * 384;
    int rt = rmn / 12, ct = rmn - rt * 12;
    long long base = (long long)b * 1572864 + (long long)(rt * 64 + r) * 768 + ct * 64 + c0;
    sr = query + base;
    dr = query_bf + base;
  }
  #pragma unroll
  for (int q = 0; q < 4; ++q) {
    float4 v = *reinterpret_cast<const float4*>(sr + q * 4);
    *reinterpret_cast<ushort4*>(dr + q * 4) =
        make_ushort4(f2bf(v.x), f2bf(v.y), f2bf(v.z), f2bf(v.w));
  }
}

// fused reductions (wide launch)
__global__ void k_sums(const unsigned short* __restrict__ WqT,
                       const unsigned short* __restrict__ WkT,
                       const float* __restrict__ bk, const float* __restrict__ bq,
                       const float* __restrict__ Mt, const int* __restrict__ mask,
                       float* __restrict__ u, float* __restrict__ w3,
                       float* __restrict__ s1, float* __restrict__ sm0) {
  int gw = blockIdx.x * 4 + (threadIdx.x >> 6);
  int lane = threadIdx.x & 63;
  if (gw < 1536) {
    const unsigned short* wrow = (gw < 768) ? (WqT + (long long)gw * 768)
                                            : (WkT + (long long)(gw - 768) * 768);
    const float* vec = (gw < 768) ? bk : bq;
    float s = 0.f;
    for (int j = lane; j < 768; j += 64) s += bf2f(wrow[j]) * vec[j];
    #pragma unroll
    for (int off = 32; off > 0; off >>= 1) s += __shfl_down(s, off, 64);
    if (lane == 0) { if (gw < 768) u[gw] = s; else w3[gw - 768] = s; }
  } else {
    int g2 = gw - 1536;
    int b = g2 / 768, d2 = g2 - b * 768;
    if (b >= 8) return;
    const int* mb = mask + b * 768;
    const float* mrow = Mt + (long long)d2 * 768;
    float a1 = 0.f, a0 = 0.f;
    for (int k = lane; k < 768; k += 64) {
      float v = mrow[k];
      if (mb[k]) a1 += v; else a0 += v;
    }
    #pragma unroll
    for (int off = 32; off > 0; off >>= 1) {
      a1 += __shfl_down(a1, off, 64);
      a0 += __shfl_down(a0, off, 64);
    }
    if (lane == 0) { s1[g2] = a1; sm0[g2] = a0; }
  }
}

// row constants (wide launch)
__global__ void k_row(const unsigned short* __restrict__ Tt, const float* __restrict__ w3,
                      const float* __restrict__ s1, const float* __restrict__ sm0,
                      const float* __restrict__ bq, const float* __restrict__ bk,
                      const float* __restrict__ bc, float* __restrict__ row) {
  int gw = blockIdx.x * 4 + (threadIdx.x >> 6);
  int lane = threadIdx.x & 63;
  int b = gw / 768, d2 = gw - b * 768;
  if (b >= 8) return;
  const unsigned short* trow = Tt + ((long long)b * 768 + d2) * 768;
  float st = 0.f, sbb = 0.f;
  for (int j = lane; j < 768; j += 64) {
    st += bf2f(trow[j]) * w3[j];
    sbb += bq[j] * bk[j];
  }
  #pragma unroll
  for (int off = 32; off > 0; off >>= 1) {
    st += __shfl_down(st, off, 64);
    sbb += __shfl_down(sbb, off, 64);
  }
  if (lane == 0)
    row[gw] = bc[d2] - 1e9f * sm0[gw] + SCALE * (st + sbb * s1[gw]);
}

// ---------------- shared small-GEMM pieces ----------------
__device__ inline void xcd_swz(int& bx, int& by, int& bz) {
  const int gx = gridDim.x, gy = gridDim.y;
  const int nwg = gx * gy * (int)gridDim.z;
  int lin = blockIdx.x + gx * (blockIdx.y + gy * blockIdx.z);
  int qq = nwg >> 3, rr = nwg & 7, xcd = lin & 7, loc = lin >> 3;
  int swz = (xcd < rr ? xcd * (qq + 1) : rr * (qq + 1) + (xcd - rr) * qq) + loc;
  bz = swz / (gx * gy);
  int rem = swz - bz * gx * gy;
  by = rem / gx;
  bx = rem - by * gx;
}

__device__ inline void nt64_core(const unsigned short* Ab, int lda,
                                 const unsigned short* Bb, int ldb,
                                 int m0, int n0, int tid, f32x4 (&acc)[2][2],
                                 char* As, char* Bs) {
  const int w = tid >> 6, lane = tid & 63;
  const int wr = w >> 1, wc = w & 1;
  const int fr = lane & 15, fq = lane >> 4;
  for (int kt = 0; kt < 768; kt += 64) {
    __syncthreads();
    #pragma unroll
    for (int t = 0; t < 2; ++t) {
      int g = t * 256 + tid;
      int row = g >> 3, s = g & 7;
      int sg = (s - row) & 7;
      const unsigned short* ga = Ab + (long long)(m0 + row) * lda + kt + sg * 8;
      __builtin_amdgcn_global_load_lds(
          (const __attribute__((address_space(1))) void*)ga,
          (__attribute__((address_space(3))) void*)(As + g * 16), 16, 0, 0);
    }
    #pragma unroll
    for (int t = 0; t < 2; ++t) {
      int g = t * 256 + tid;
      int row = g >> 3, s = g & 7;
      int sg = (s - row) & 7;
      const unsigned short* gb = Bb + (long long)(n0 + row) * ldb + kt + sg * 8;
      __builtin_amdgcn_global_load_lds(
          (const __attribute__((address_space(1))) void*)gb,
          (__attribute__((address_space(3))) void*)(Bs + g * 16), 16, 0, 0);
    }
    __syncthreads();
    #pragma unroll
    for (int kk = 0; kk < 2; ++kk) {
      short8 af[2], bfr[2];
      #pragma unroll
      for (int i = 0; i < 2; ++i) {
        int r = wr * 32 + i * 16 + fr;
        af[i] = *reinterpret_cast<const short8*>(As + r * 128 + (((kk * 4 + fq) + r) & 7) * 16);
      }
      #pragma unroll
      for (int j = 0; j < 2; ++j) {
        int r = wc * 32 + j * 16 + fr;
        bfr[j] = *reinterpret_cast<const short8*>(Bs + r * 128 + (((kk * 4 + fq) + r) & 7) * 16);
      }
      #pragma unroll
      for (int i = 0; i < 2; ++i)
        #pragma unroll
        for (int j = 0; j < 2; ++j)
          acc[i][j] = __builtin_amdgcn_mfma_f32_16x16x32_bf16(af[i], bfr[j], acc[i][j], 0, 0, 0);
    }
  }
}

// fused G1 (z=0) + W2 (z=1)
__global__ __launch_bounds__(256) void gemm_g1w2(
    const unsigned short* __restrict__ Wc2_bf, const unsigned short* __restrict__ prev_bf,
    const unsigned short* __restrict__ WqT_bf, const unsigned short* __restrict__ WkT_bf,
    const float* __restrict__ Wc, float* __restrict__ Mt_f,
    unsigned short* __restrict__ Mt_bf, unsigned short* __restrict__ W2_bf)
{
  __shared__ __align__(16) char As[64 * 128];
  __shared__ __align__(16) char Bs[64 * 128];
  int bx, by, bz;
  xcd_swz(bx, by, bz);
  const int m0 = by * 64, n0 = bx * 64;
  const unsigned short* A = bz ? WqT_bf : Wc2_bf;
  const unsigned short* B = bz ? WkT_bf : prev_bf;
  const int tid = threadIdx.x;
  f32x4 acc[2][2] = {};
  nt64_core(A, 768, B, 768, m0, n0, tid, acc, As, Bs);

  const int w = tid >> 6, lane = tid & 63;
  const int wr = w >> 1, wc = w & 1;
  const int fr = lane & 15, fq = lane >> 4;
  #pragma unroll
  for (int i = 0; i < 2; ++i)
    #pragma unroll
    for (int j = 0; j < 2; ++j)
      #pragma unroll
      for (int r = 0; r < 4; ++r) {
        int row = m0 + wr * 32 + i * 16 + fq * 4 + r;
        int col = n0 + wc * 32 + j * 16 + fr;
        float v = acc[i][j][r];
        if (bz == 0) {
          v += Wc[(long long)row * 1536 + col];
          Mt_f[(long long)row * 768 + col] = v;
          Mt_bf[(long long)row * 768 + col] = f2bf(v);
        } else {
          W2_bf[(long long)row * 768 + col] = f2bf(v);
        }
      }
}

// ---------------- g34_pipe: 96x192 1-barrier counted GEMM (r15 proven) --------
template <int MODE>
__global__ __launch_bounds__(512, 1) void g34_pipe(
    const unsigned short* __restrict__ A, long long aStr,
    const unsigned short* __restrict__ B, long long bStr,
    unsigned short* __restrict__ C,
    const float* __restrict__ s1, const float* __restrict__ uv)
{
  __shared__ __align__(16) char As[3][96 * 128];    // 3 x 12 KB
  __shared__ __align__(16) char Bs[2][192 * 128];   // 2 x 24 KB

  int lin = blockIdx.x + 4 * (blockIdx.y + 8 * blockIdx.z);
  int swz = (lin & 7) * 32 + (lin >> 3);
  int bz = swz >> 5;
  int rem = swz & 31;
  int by = rem >> 2, bx = rem & 3;

  const int tid = threadIdx.x;
  const int wv = tid >> 6, lane = tid & 63;
  const int b = bz;
  const int m0 = by * 96, n0 = bx * 192;
  const unsigned short* Ab = A + (long long)b * aStr;
  const unsigned short* Bb = B + (long long)b * bStr;
  const int wr = wv >> 2, wn = wv & 3;
  const int fr = lane & 15, fq = lane >> 4;

  f32x4 acc[3][3] = {};

  auto stageA = [&](int buf, int kt) {
    #pragma unroll
    for (int s = 0; s < 2; ++s) {
      int g = s * 512 + tid;
      if (g < 768) {
        int row = g >> 3, slot = g & 7;
        int sg = (slot - row) & 7;
        const unsigned short* ga = Ab + (long long)(m0 + row) * 768 + kt + sg * 8;
        __builtin_amdgcn_global_load_lds(
            (const __attribute__((address_space(1))) void*)ga,
            (__attribute__((address_space(3))) void*)(&As[buf][0] + g * 16), 16, 0, 0);
      }
    }
  };
  auto stageB = [&](int buf, int kt) {
    #pragma unroll
    for (int s = 0; s < 3; ++s) {
      int g = s * 512 + tid;
      int row = g >> 3, slot = g & 7;
      int sg = (slot - row) & 7;
      const unsigned short* gb = Bb + (long long)(n0 + row) * 768 + kt + sg * 8;
      __builtin_amdgcn_global_load_lds(
          (const __attribute__((address_space(1))) void*)gb,
          (__attribute__((address_space(3))) void*)(&Bs[buf][0] + g * 16), 16, 0, 0);
    }
  };

  stageA(0, 0);
  stageB(0, 0);
  stageA(1, 64);
  asm volatile("s_waitcnt vmcnt(1)" ::: "memory");
  __builtin_amdgcn_s_barrier();

  for (int t = 0; t < 12; ++t) {
    const char* as = &As[t % 3][0];
    const char* bs = &Bs[t & 1][0];

    if (t < 11) stageB((t + 1) & 1, (t + 1) * 64);
    if (t < 10) stageA((t + 2) % 3, (t + 2) * 64);

    #pragma unroll
    for (int kk = 0; kk < 2; ++kk) {
      short8 a[3], bb[3];
      #pragma unroll
      for (int i = 0; i < 3; ++i) {
        int r = wr * 48 + i * 16 + fr;
        a[i] = *reinterpret_cast<const short8*>(as + r * 128 + (((kk * 4 + fq) + r) & 7) * 16);
      }
      #pragma unroll
      for (int j = 0; j < 3; ++j) {
        int r = wn * 48 + j * 16 + fr;
        bb[j] = *reinterpret_cast<const short8*>(bs + r * 128 + (((kk * 4 + fq) + r) & 7) * 16);
      }
      __builtin_amdgcn_s_setprio(1);
      #pragma unroll
      for (int i = 0; i < 3; ++i)
        #pragma unroll
        for (int j = 0; j < 3; ++j)
          acc[i][j] = __builtin_amdgcn_mfma_f32_16x16x32_bf16(a[i], bb[j], acc[i][j], 0, 0, 0);
      __builtin_amdgcn_s_setprio(0);
    }

    if (t < 10)       asm volatile("s_waitcnt vmcnt(1)" ::: "memory");
    else if (t == 10) asm volatile("s_waitcnt vmcnt(0)" ::: "memory");
    __builtin_amdgcn_s_barrier();
  }

  #pragma unroll
  for (int i = 0; i < 3; ++i)
    #pragma unroll
    for (int j = 0; j < 3; ++j)
      #pragma unroll
      for (int r = 0; r < 4; ++r) {
        int row = m0 + wr * 48 + i * 16 + fq * 4 + r;
        int col = n0 + wn * 48 + j * 16 + fr;
        float v = acc[i][j][r];
        if constexpr (MODE == 4) v += s1[b * 768 + row] * uv[col];
        C[(long long)b * 589824 + (long long)row * 768 + col] = f2bf(v);
      }
}

// ---------------- G5: 32x32x16 MFMA, 1-barrier counted pipeline (r16) ----------
// waves 4M x 2N, per-wave 64x96, acc[2][3] of f32x16
__global__ __launch_bounds__(512, 1) void g5_pipe(
    const unsigned short* __restrict__ A,   // query_bf [8][2048][768]
    const unsigned short* __restrict__ B,   // Pt [8][768][768]
    float* __restrict__ C, const float* __restrict__ rowv)
{
  __shared__ __align__(16) char As[3][256 * 128];   // 3 x 32 KB
  __shared__ __align__(16) char Bs[2][192 * 128];   // 2 x 24 KB

  int lin = blockIdx.x + 4 * (blockIdx.y + 8 * blockIdx.z);
  int swz = (lin & 7) * 32 + (lin >> 3);
  int bz = swz >> 5;
  int rem = swz & 31;
  int by = rem >> 2, bx = rem & 3;

  const int b = bz;
  const int m0 = by * 256, n0 = bx * 192;
  const unsigned short* Ab = A + (long long)b * 1572864;
  const unsigned short* Bb = B + (long long)b * 589824;

  const int tid = threadIdx.x;
  const int w = tid >> 6, lane = tid & 63;
  const int wm = w >> 1, wn = w & 1;       // 4 M-waves x 2 N-waves
  const int l31 = lane & 31, lh = lane >> 5;

  f32x16 acc[2][3] = {};

  auto stageA = [&](int buf, int kt) {
    #pragma unroll
    for (int s = 0; s < 4; ++s) {
      int g = s * 512 + tid;
      int row = g >> 3, slot = g & 7;
      int sg = (slot - row) & 7;
      const unsigned short* ga = Ab + (long long)(m0 + row) * 768 + kt + sg * 8;
      __builtin_amdgcn_global_load_lds(
          (const __attribute__((address_space(1))) void*)ga,
          (__attribute__((address_space(3))) void*)(&As[buf][0] + g * 16), 16, 0, 0);
    }
  };
  auto stageB = [&](int buf, int kt) {
    #pragma unroll
    for (int s = 0; s < 3; ++s) {
      int g = s * 512 + tid;
      int row = g >> 3, slot = g & 7;
      int sg = (slot - row) & 7;
      const unsigned short* gb = Bb + (long long)(n0 + row) * 768 + kt + sg * 8;
      __builtin_amdgcn_global_load_lds(
          (const __attribute__((address_space(1))) void*)gb,
          (__attribute__((address_space(3))) void*)(&Bs[buf][0] + g * 16), 16, 0, 0);
    }
  };

  stageA(0, 0);
  stageB(0, 0);
  stageA(1, 64);
  asm volatile("s_waitcnt vmcnt(4)" ::: "memory");
  __builtin_amdgcn_s_barrier();

  for (int t = 0; t < 12; ++t) {
    const char* as = &As[t % 3][0];
    const char* bs = &Bs[t & 1][0];

    if (t < 11) stageB((t + 1) & 1, (t + 1) * 64);
    if (t < 10) stageA((t + 2) % 3, (t + 2) * 64);

    // 4 k-chunks of 16; frag: row=lane&31, k=(lane>>5)*8+j -> granule kc*2+lh
    #pragma unroll
    for (int kc = 0; kc < 4; ++kc) {
      const int g = kc * 2 + lh;
      short8 a[2], bb[3];
      #pragma unroll
      for (int i = 0; i < 2; ++i) {
        int r = wm * 64 + i * 32 + l31;
        a[i] = *reinterpret_cast<const short8*>(as + r * 128 + ((g + r) & 7) * 16);
      }
      #pragma unroll
      for (int j = 0; j < 3; ++j) {
        int r = wn * 96 + j * 32 + l31;
        bb[j] = *reinterpret_cast<const short8*>(bs + r * 128 + ((g + r) & 7) * 16);
      }
      __builtin_amdgcn_s_setprio(1);
      #pragma unroll
      for (int i = 0; i < 2; ++i)
        #pragma unroll
        for (int j = 0; j < 3; ++j)
          acc[i][j] = __builtin_amdgcn_mfma_f32_32x32x16_bf16(a[i], bb[j], acc[i][j], 0, 0, 0);
      __builtin_amdgcn_s_setprio(0);
    }

    if (t < 10)       asm volatile("s_waitcnt vmcnt(4)" ::: "memory");
    else if (t == 10) asm volatile("s_waitcnt vmcnt(0)" ::: "memory");
    __builtin_amdgcn_s_barrier();
  }

  // epilogue: 32x32 C/D layout (m74/m101): col=lane&31,
  // row=(reg&3)+8*(reg>>2)+4*(lane>>5)
  const long long ob = (long long)b * 1572864;
  #pragma unroll
  for (int i = 0; i < 2; ++i)
    #pragma unroll
    for (int j = 0; j < 3; ++j)
      #pragma unroll
      for (int reg = 0; reg < 16; ++reg) {
        int row = m0 + wm * 64 + i * 32 + (reg & 3) + 8 * (reg >> 2) + 4 * lh;
        int col = n0 + wn * 96 + j * 32 + l31;
        C[ob + (long long)row * 768 + col] = acc[i][j][reg] * SCALE + rowv[b * 768 + col];
      }
}

extern "C" void kernel_launch(void* const* d_in, const int* in_sizes, int n_in,
                              void* d_out, int out_size, void* d_ws, size_t ws_size,
                              hipStream_t stream)
{
  const float* query = (const float*)d_in[0];
  const float* key   = (const float*)d_in[1];
  const float* prev  = (const float*)d_in[3];
  const int*   mask  = (const int*)d_in[4];
  const float* Wq    = (const float*)d_in[5];
  const float* bq    = (const float*)d_in[6];
  const float* Wk    = (const float*)d_in[7];
  const float* bk    = (const float*)d_in[8];
  const float* Wc    = (const float*)d_in[11];
  const float* bc    = (const float*)d_in[12];
  float* out = (float*)d_out;

  char* p = (char*)d_ws;
  size_t off = 0;
  auto alloc = [&](size_t bytes) {
    char* r = p + off;
    off += (bytes + 255) & ~(size_t)255;
    return r;
  };
  unsigned short* query_bf = (unsigned short*)alloc(12582912ull * 2);
  unsigned short* keyzT_bf = (unsigned short*)alloc(4718592ull * 2);
  unsigned short* WqT_bf   = (unsigned short*)alloc(589824ull * 2);
  unsigned short* WkT_bf   = (unsigned short*)alloc(589824ull * 2);
  unsigned short* prev_bf  = (unsigned short*)alloc(589824ull * 2);
  unsigned short* Wc2_bf   = (unsigned short*)alloc(589824ull * 2);
  float*          Mt_f     = (float*)alloc(589824ull * 4);
  unsigned short* Mt_bf    = (unsigned short*)alloc(589824ull * 2);
  unsigned short* W2_bf    = (unsigned short*)alloc(589824ull * 2);
  unsigned short* Tt_bf    = (unsigned short*)alloc(4718592ull * 2);
  unsigned short* Pt_bf    = (unsigned short*)alloc(4718592ull * 2);
  float*          s1f      = (float*)alloc(6144ull * 4);
  float*          sm0f     = (float*)alloc(6144ull * 4);
  float*          uv       = (float*)alloc(768ull * 4);
  float*          w3v      = (float*)alloc(768ull * 4);
  float*          rowv     = (float*)alloc(6144ull * 4);
  (void)ws_size; (void)in_sizes; (void)n_in; (void)out_size;

  // 1) all conversions/transposes
  k_prep_all<<<dim3(12, 12, 34), dim3(256), 0, stream>>>(
      Wq, Wk, key, mask, prev, Wc, query,
      WqT_bf, WkT_bf, keyzT_bf, prev_bf, Wc2_bf, query_bf);
  // 2) G1 + W2
  gemm_g1w2<<<dim3(12, 12, 2), dim3(256), 0, stream>>>(
      Wc2_bf, prev_bf, WqT_bf, WkT_bf, Wc, Mt_f, Mt_bf, W2_bf);
  // 3) u, w3, s1, sm0 (wide launch)
  k_sums<<<dim3(1920), dim3(256), 0, stream>>>(WqT_bf, WkT_bf, bk, bq, Mt_f, mask,
                                               uv, w3v, s1f, sm0f);
  // 4) G3': Tt[b] = NT(Mt, keyzT[b])
  g34_pipe<3><<<dim3(4, 8, 8), dim3(512), 0, stream>>>(
      Mt_bf, 0ll, keyzT_bf, 589824ll, Tt_bf,
      (const float*)nullptr, (const float*)nullptr);
  // 5) G4': Pt[b] = NT(Tt[b], W2) + s1[b][m]*u[n]
  g34_pipe<4><<<dim3(4, 8, 8), dim3(512), 0, stream>>>(
      Tt_bf, 589824ll, W2_bf, 0ll, Pt_bf, s1f, uv);
  // 6) row constants (wide launch)
  k_row<<<dim3(1536), dim3(256), 0, stream>>>(Tt_bf, w3v, s1f, sm0f, bq, bk, bc, rowv);
  // 7) G5 (32x32x16)
  g5_pipe<<<dim3(4, 8, 8), dim3(512), 0, stream>>>(query_bf, Pt_bf, out, rowv);
}

// Round 17
// 106.983 us; speedup vs baseline: 1.0093x; 1.0093x over previous
//
#include <hip/hip_runtime.h>
#include <hip/hip_bf16.h>

// out[b] = SCALE*query[b]@P[b] + row[b]
//   M  = Wc1^T + prev@Wc2^T ; Tt[b] = NT(Mt, keyzT[b]) ; W2 = Wq^T@Wk
//   u = Wq^T bk ; w3 = Wk^T bq ; Pt[b] = NT(Tt[b], W2) + s1*u rank-1
//   row[b][d] = bc - 1e9*sm0 + SCALE*(w3@T[b] + (bq.bk)*s1)
// r17: k_prep_all rewritten for store width (prep was 39us at 2TB/s, 25% BW,
// VALU 5% -> width-bound): transpose regions now 16 contiguous bf16/thread
// (2x short8 stores, was 2B/lane); cvt regions 8 contiguous elem/thread
// (1x short8 store/lane, 100% density). Bit-identical numerics.
// GEMMs frozen from r16: 1-barrier/K-tile counted-vmcnt pipelines, rotation
// LDS swizzle (0 conflicts), XCD swizzle; g5 on 32x32x16 MFMA.

typedef __attribute__((ext_vector_type(8))) short short8;
typedef __attribute__((ext_vector_type(4))) float f32x4;
typedef __attribute__((ext_vector_type(16))) float f32x16;

#define SCALE 0.03608439182435161f   /* 1/sqrt(768) */

__device__ inline unsigned short f2bf(float x) {
  unsigned int u = __builtin_bit_cast(unsigned int, x);
  u = (u + 0x7fffu + ((u >> 16) & 1u)) >> 16;   // RNE
  return (unsigned short)u;
}
__device__ inline float bf2f(unsigned short h) {
  return __builtin_bit_cast(float, ((unsigned int)h) << 16);
}

// ---------------- fused prep: grid (12,12,57) ----------------
// z=0: WqT, z=1: WkT, z=2..9: keyzT[b]   (transpose, wide 16-elem stores)
// z=10..11: prev cvt, z=12..13: Wc2 cvt, z=14..56: query cvt (8 elem/thread)
__global__ void k_prep_all(
    const float* __restrict__ Wq, const float* __restrict__ Wk,
    const float* __restrict__ key, const int* __restrict__ mask,
    const float* __restrict__ prev, const float* __restrict__ Wc,
    const float* __restrict__ query,
    unsigned short* __restrict__ WqT, unsigned short* __restrict__ WkT,
    unsigned short* __restrict__ keyzT, unsigned short* __restrict__ prev_bf,
    unsigned short* __restrict__ Wc2_bf, unsigned short* __restrict__ query_bf)
{
  __shared__ float t[64][65];
  const int z = blockIdx.z;
  const int tid = threadIdx.x;
  if (z < 10) {                       // transpose+cvt, wide stores
    const float* src;
    unsigned short* dst;
    const int* mb = nullptr;
    if (z == 0) { src = Wq; dst = WqT; }
    else if (z == 1) { src = Wk; dst = WkT; }
    else {
      int b = z - 2;
      src = key + (long long)b * 589824;
      dst = keyzT + (long long)b * 589824;
      mb = mask + b * 768;
    }
    int bx = blockIdx.x * 64, by = blockIdx.y * 64;
    int tx = tid & 63, ty = tid >> 6;
    #pragma unroll
    for (int i = 0; i < 64; i += 4) {          // t[k_local][d1_local]
      float v = src[(long long)(by + ty + i) * 768 + bx + tx];
      if (mb) v = mb[by + ty + i] ? v : 0.0f;
      t[ty + i][tx] = v;
    }
    __syncthreads();
    // thread -> output row (d1) orow = tid>>2, 16 contiguous k at oc
    int orow = tid >> 2, oc = (tid & 3) * 16;
    short8 s0, s1;
    #pragma unroll
    for (int q = 0; q < 8; ++q) s0[q] = (short)f2bf(t[oc + q][orow]);
    #pragma unroll
    for (int q = 0; q < 8; ++q) s1[q] = (short)f2bf(t[oc + 8 + q][orow]);
    unsigned short* dp = dst + (long long)(bx + orow) * 768 + by + oc;
    *reinterpret_cast<short8*>(dp) = s0;
    *reinterpret_cast<short8*>(dp + 8) = s1;
    return;
  }
  // contiguous-cvt regions: 8 elements per thread, short8 store
  const float* sr;
  unsigned short* dr;
  if (z < 12) {                        // prev: 589824 elems = 2 slices
    int grp = ((z - 10) * 144 + blockIdx.y * 12 + blockIdx.x) * 256 + tid;
    sr = prev + (long long)grp * 8;
    dr = prev_bf + (long long)grp * 8;
  } else if (z < 14) {                 // Wc2 slice: row stride 1536 source
    int grp = ((z - 12) * 144 + blockIdx.y * 12 + blockIdx.x) * 256 + tid;
    int r = grp / 96, c = (grp - r * 96) * 8;
    sr = Wc + (long long)r * 1536 + 768 + c;
    dr = Wc2_bf + (long long)r * 768 + c;
  } else {                             // query: 1572864 groups, guard
    int tz = ((z - 14) * 144 + blockIdx.y * 12 + blockIdx.x);
    long long grp = (long long)tz * 256 + tid;
    if (grp >= 1572864) return;
    sr = query + grp * 8;
    dr = query_bf + grp * 8;
  }
  float4 v0 = *reinterpret_cast<const float4*>(sr);
  float4 v1 = *reinterpret_cast<const float4*>(sr + 4);
  short8 o;
  o[0] = (short)f2bf(v0.x); o[1] = (short)f2bf(v0.y);
  o[2] = (short)f2bf(v0.z); o[3] = (short)f2bf(v0.w);
  o[4] = (short)f2bf(v1.x); o[5] = (short)f2bf(v1.y);
  o[6] = (short)f2bf(v1.z); o[7] = (short)f2bf(v1.w);
  *reinterpret_cast<short8*>(dr) = o;
}

// fused reductions (wide launch)
__global__ void k_sums(const unsigned short* __restrict__ WqT,
                       const unsigned short* __restrict__ WkT,
                       const float* __restrict__ bk, const float* __restrict__ bq,
                       const float* __restrict__ Mt, const int* __restrict__ mask,
                       float* __restrict__ u, float* __restrict__ w3,
                       float* __restrict__ s1, float* __restrict__ sm0) {
  int gw = blockIdx.x * 4 + (threadIdx.x >> 6);
  int lane = threadIdx.x & 63;
  if (gw < 1536) {
    const unsigned short* wrow = (gw < 768) ? (WqT + (long long)gw * 768)
                                            : (WkT + (long long)(gw - 768) * 768);
    const float* vec = (gw < 768) ? bk : bq;
    float s = 0.f;
    for (int j = lane; j < 768; j += 64) s += bf2f(wrow[j]) * vec[j];
    #pragma unroll
    for (int off = 32; off > 0; off >>= 1) s += __shfl_down(s, off, 64);
    if (lane == 0) { if (gw < 768) u[gw] = s; else w3[gw - 768] = s; }
  } else {
    int g2 = gw - 1536;
    int b = g2 / 768, d2 = g2 - b * 768;
    if (b >= 8) return;
    const int* mb = mask + b * 768;
    const float* mrow = Mt + (long long)d2 * 768;
    float a1 = 0.f, a0 = 0.f;
    for (int k = lane; k < 768; k += 64) {
      float v = mrow[k];
      if (mb[k]) a1 += v; else a0 += v;
    }
    #pragma unroll
    for (int off = 32; off > 0; off >>= 1) {
      a1 += __shfl_down(a1, off, 64);
      a0 += __shfl_down(a0, off, 64);
    }
    if (lane == 0) { s1[g2] = a1; sm0[g2] = a0; }
  }
}

// row constants (wide launch)
__global__ void k_row(const unsigned short* __restrict__ Tt, const float* __restrict__ w3,
                      const float* __restrict__ s1, const float* __restrict__ sm0,
                      const float* __restrict__ bq, const float* __restrict__ bk,
                      const float* __restrict__ bc, float* __restrict__ row) {
  int gw = blockIdx.x * 4 + (threadIdx.x >> 6);
  int lane = threadIdx.x & 63;
  int b = gw / 768, d2 = gw - b * 768;
  if (b >= 8) return;
  const unsigned short* trow = Tt + ((long long)b * 768 + d2) * 768;
  float st = 0.f, sbb = 0.f;
  for (int j = lane; j < 768; j += 64) {
    st += bf2f(trow[j]) * w3[j];
    sbb += bq[j] * bk[j];
  }
  #pragma unroll
  for (int off = 32; off > 0; off >>= 1) {
    st += __shfl_down(st, off, 64);
    sbb += __shfl_down(sbb, off, 64);
  }
  if (lane == 0)
    row[gw] = bc[d2] - 1e9f * sm0[gw] + SCALE * (st + sbb * s1[gw]);
}

// ---------------- shared small-GEMM pieces ----------------
__device__ inline void xcd_swz(int& bx, int& by, int& bz) {
  const int gx = gridDim.x, gy = gridDim.y;
  const int nwg = gx * gy * (int)gridDim.z;
  int lin = blockIdx.x + gx * (blockIdx.y + gy * blockIdx.z);
  int qq = nwg >> 3, rr = nwg & 7, xcd = lin & 7, loc = lin >> 3;
  int swz = (xcd < rr ? xcd * (qq + 1) : rr * (qq + 1) + (xcd - rr) * qq) + loc;
  bz = swz / (gx * gy);
  int rem = swz - bz * gx * gy;
  by = rem / gx;
  bx = rem - by * gx;
}

__device__ inline void nt64_core(const unsigned short* Ab, int lda,
                                 const unsigned short* Bb, int ldb,
                                 int m0, int n0, int tid, f32x4 (&acc)[2][2],
                                 char* As, char* Bs) {
  const int w = tid >> 6, lane = tid & 63;
  const int wr = w >> 1, wc = w & 1;
  const int fr = lane & 15, fq = lane >> 4;
  for (int kt = 0; kt < 768; kt += 64) {
    __syncthreads();
    #pragma unroll
    for (int t = 0; t < 2; ++t) {
      int g = t * 256 + tid;
      int row = g >> 3, s = g & 7;
      int sg = (s - row) & 7;
      const unsigned short* ga = Ab + (long long)(m0 + row) * lda + kt + sg * 8;
      __builtin_amdgcn_global_load_lds(
          (const __attribute__((address_space(1))) void*)ga,
          (__attribute__((address_space(3))) void*)(As + g * 16), 16, 0, 0);
    }
    #pragma unroll
    for (int t = 0; t < 2; ++t) {
      int g = t * 256 + tid;
      int row = g >> 3, s = g & 7;
      int sg = (s - row) & 7;
      const unsigned short* gb = Bb + (long long)(n0 + row) * ldb + kt + sg * 8;
      __builtin_amdgcn_global_load_lds(
          (const __attribute__((address_space(1))) void*)gb,
          (__attribute__((address_space(3))) void*)(Bs + g * 16), 16, 0, 0);
    }
    __syncthreads();
    #pragma unroll
    for (int kk = 0; kk < 2; ++kk) {
      short8 af[2], bfr[2];
      #pragma unroll
      for (int i = 0; i < 2; ++i) {
        int r = wr * 32 + i * 16 + fr;
        af[i] = *reinterpret_cast<const short8*>(As + r * 128 + (((kk * 4 + fq) + r) & 7) * 16);
      }
      #pragma unroll
      for (int j = 0; j < 2; ++j) {
        int r = wc * 32 + j * 16 + fr;
        bfr[j] = *reinterpret_cast<const short8*>(Bs + r * 128 + (((kk * 4 + fq) + r) & 7) * 16);
      }
      #pragma unroll
      for (int i = 0; i < 2; ++i)
        #pragma unroll
        for (int j = 0; j < 2; ++j)
          acc[i][j] = __builtin_amdgcn_mfma_f32_16x16x32_bf16(af[i], bfr[j], acc[i][j], 0, 0, 0);
    }
  }
}

// fused G1 (z=0) + W2 (z=1)
__global__ __launch_bounds__(256) void gemm_g1w2(
    const unsigned short* __restrict__ Wc2_bf, const unsigned short* __restrict__ prev_bf,
    const unsigned short* __restrict__ WqT_bf, const unsigned short* __restrict__ WkT_bf,
    const float* __restrict__ Wc, float* __restrict__ Mt_f,
    unsigned short* __restrict__ Mt_bf, unsigned short* __restrict__ W2_bf)
{
  __shared__ __align__(16) char As[64 * 128];
  __shared__ __align__(16) char Bs[64 * 128];
  int bx, by, bz;
  xcd_swz(bx, by, bz);
  const int m0 = by * 64, n0 = bx * 64;
  const unsigned short* A = bz ? WqT_bf : Wc2_bf;
  const unsigned short* B = bz ? WkT_bf : prev_bf;
  const int tid = threadIdx.x;
  f32x4 acc[2][2] = {};
  nt64_core(A, 768, B, 768, m0, n0, tid, acc, As, Bs);

  const int w = tid >> 6, lane = tid & 63;
  const int wr = w >> 1, wc = w & 1;
  const int fr = lane & 15, fq = lane >> 4;
  #pragma unroll
  for (int i = 0; i < 2; ++i)
    #pragma unroll
    for (int j = 0; j < 2; ++j)
      #pragma unroll
      for (int r = 0; r < 4; ++r) {
        int row = m0 + wr * 32 + i * 16 + fq * 4 + r;
        int col = n0 + wc * 32 + j * 16 + fr;
        float v = acc[i][j][r];
        if (bz == 0) {
          v += Wc[(long long)row * 1536 + col];
          Mt_f[(long long)row * 768 + col] = v;
          Mt_bf[(long long)row * 768 + col] = f2bf(v);
        } else {
          W2_bf[(long long)row * 768 + col] = f2bf(v);
        }
      }
}

// ---------------- g34_pipe: 96x192 1-barrier counted GEMM (r15 proven) --------
template <int MODE>
__global__ __launch_bounds__(512, 1) void g34_pipe(
    const unsigned short* __restrict__ A, long long aStr,
    const unsigned short* __restrict__ B, long long bStr,
    unsigned short* __restrict__ C,
    const float* __restrict__ s1, const float* __restrict__ uv)
{
  __shared__ __align__(16) char As[3][96 * 128];    // 3 x 12 KB
  __shared__ __align__(16) char Bs[2][192 * 128];   // 2 x 24 KB

  int lin = blockIdx.x + 4 * (blockIdx.y + 8 * blockIdx.z);
  int swz = (lin & 7) * 32 + (lin >> 3);
  int bz = swz >> 5;
  int rem = swz & 31;
  int by = rem >> 2, bx = rem & 3;

  const int tid = threadIdx.x;
  const int wv = tid >> 6, lane = tid & 63;
  const int b = bz;
  const int m0 = by * 96, n0 = bx * 192;
  const unsigned short* Ab = A + (long long)b * aStr;
  const unsigned short* Bb = B + (long long)b * bStr;
  const int wr = wv >> 2, wn = wv & 3;
  const int fr = lane & 15, fq = lane >> 4;

  f32x4 acc[3][3] = {};

  auto stageA = [&](int buf, int kt) {
    #pragma unroll
    for (int s = 0; s < 2; ++s) {
      int g = s * 512 + tid;
      if (g < 768) {
        int row = g >> 3, slot = g & 7;
        int sg = (slot - row) & 7;
        const unsigned short* ga = Ab + (long long)(m0 + row) * 768 + kt + sg * 8;
        __builtin_amdgcn_global_load_lds(
            (const __attribute__((address_space(1))) void*)ga,
            (__attribute__((address_space(3))) void*)(&As[buf][0] + g * 16), 16, 0, 0);
      }
    }
  };
  auto stageB = [&](int buf, int kt) {
    #pragma unroll
    for (int s = 0; s < 3; ++s) {
      int g = s * 512 + tid;
      int row = g >> 3, slot = g & 7;
      int sg = (slot - row) & 7;
      const unsigned short* gb = Bb + (long long)(n0 + row) * 768 + kt + sg * 8;
      __builtin_amdgcn_global_load_lds(
          (const __attribute__((address_space(1))) void*)gb,
          (__attribute__((address_space(3))) void*)(&Bs[buf][0] + g * 16), 16, 0, 0);
    }
  };

  stageA(0, 0);
  stageB(0, 0);
  stageA(1, 64);
  asm volatile("s_waitcnt vmcnt(1)" ::: "memory");
  __builtin_amdgcn_s_barrier();

  for (int t = 0; t < 12; ++t) {
    const char* as = &As[t % 3][0];
    const char* bs = &Bs[t & 1][0];

    if (t < 11) stageB((t + 1) & 1, (t + 1) * 64);
    if (t < 10) stageA((t + 2) % 3, (t + 2) * 64);

    #pragma unroll
    for (int kk = 0; kk < 2; ++kk) {
      short8 a[3], bb[3];
      #pragma unroll
      for (int i = 0; i < 3; ++i) {
        int r = wr * 48 + i * 16 + fr;
        a[i] = *reinterpret_cast<const short8*>(as + r * 128 + (((kk * 4 + fq) + r) & 7) * 16);
      }
      #pragma unroll
      for (int j = 0; j < 3; ++j) {
        int r = wn * 48 + j * 16 + fr;
        bb[j] = *reinterpret_cast<const short8*>(bs + r * 128 + (((kk * 4 + fq) + r) & 7) * 16);
      }
      __builtin_amdgcn_s_setprio(1);
      #pragma unroll
      for (int i = 0; i < 3; ++i)
        #pragma unroll
        for (int j = 0; j < 3; ++j)
          acc[i][j] = __builtin_amdgcn_mfma_f32_16x16x32_bf16(a[i], bb[j], acc[i][j], 0, 0, 0);
      __builtin_amdgcn_s_setprio(0);
    }

    if (t < 10)       asm volatile("s_waitcnt vmcnt(1)" ::: "memory");
    else if (t == 10) asm volatile("s_waitcnt vmcnt(0)" ::: "memory");
    __builtin_amdgcn_s_barrier();
  }

  #pragma unroll
  for (int i = 0; i < 3; ++i)
    #pragma unroll
    for (int j = 0; j < 3; ++j)
      #pragma unroll
      for (int r = 0; r < 4; ++r) {
        int row = m0 + wr * 48 + i * 16 + fq * 4 + r;
        int col = n0 + wn * 48 + j * 16 + fr;
        float v = acc[i][j][r];
        if constexpr (MODE == 4) v += s1[b * 768 + row] * uv[col];
        C[(long long)b * 589824 + (long long)row * 768 + col] = f2bf(v);
      }
}

// ---------------- G5: 32x32x16 MFMA, 1-barrier counted pipeline (r16) ----------
__global__ __launch_bounds__(512, 1) void g5_pipe(
    const unsigned short* __restrict__ A,   // query_bf [8][2048][768]
    const unsigned short* __restrict__ B,   // Pt [8][768][768]
    float* __restrict__ C, const float* __restrict__ rowv)
{
  __shared__ __align__(16) char As[3][256 * 128];   // 3 x 32 KB
  __shared__ __align__(16) char Bs[2][192 * 128];   // 2 x 24 KB

  int lin = blockIdx.x + 4 * (blockIdx.y + 8 * blockIdx.z);
  int swz = (lin & 7) * 32 + (lin >> 3);
  int bz = swz >> 5;
  int rem = swz & 31;
  int by = rem >> 2, bx = rem & 3;

  const int b = bz;
  const int m0 = by * 256, n0 = bx * 192;
  const unsigned short* Ab = A + (long long)b * 1572864;
  const unsigned short* Bb = B + (long long)b * 589824;

  const int tid = threadIdx.x;
  const int w = tid >> 6, lane = tid & 63;
  const int wm = w >> 1, wn = w & 1;       // 4 M-waves x 2 N-waves
  const int l31 = lane & 31, lh = lane >> 5;

  f32x16 acc[2][3] = {};

  auto stageA = [&](int buf, int kt) {
    #pragma unroll
    for (int s = 0; s < 4; ++s) {
      int g = s * 512 + tid;
      int row = g >> 3, slot = g & 7;
      int sg = (slot - row) & 7;
      const unsigned short* ga = Ab + (long long)(m0 + row) * 768 + kt + sg * 8;
      __builtin_amdgcn_global_load_lds(
          (const __attribute__((address_space(1))) void*)ga,
          (__attribute__((address_space(3))) void*)(&As[buf][0] + g * 16), 16, 0, 0);
    }
  };
  auto stageB = [&](int buf, int kt) {
    #pragma unroll
    for (int s = 0; s < 3; ++s) {
      int g = s * 512 + tid;
      int row = g >> 3, slot = g & 7;
      int sg = (slot - row) & 7;
      const unsigned short* gb = Bb + (long long)(n0 + row) * 768 + kt + sg * 8;
      __builtin_amdgcn_global_load_lds(
          (const __attribute__((address_space(1))) void*)gb,
          (__attribute__((address_space(3))) void*)(&Bs[buf][0] + g * 16), 16, 0, 0);
    }
  };

  stageA(0, 0);
  stageB(0, 0);
  stageA(1, 64);
  asm volatile("s_waitcnt vmcnt(4)" ::: "memory");
  __builtin_amdgcn_s_barrier();

  for (int t = 0; t < 12; ++t) {
    const char* as = &As[t % 3][0];
    const char* bs = &Bs[t & 1][0];

    if (t < 11) stageB((t + 1) & 1, (t + 1) * 64);
    if (t < 10) stageA((t + 2) % 3, (t + 2) * 64);

    // 4 k-chunks of 16; frag: row=lane&31, k=(lane>>5)*8+j -> granule kc*2+lh
    #pragma unroll
    for (int kc = 0; kc < 4; ++kc) {
      const int g = kc * 2 + lh;
      short8 a[2], bb[3];
      #pragma unroll
      for (int i = 0; i < 2; ++i) {
        int r = wm * 64 + i * 32 + l31;
        a[i] = *reinterpret_cast<const short8*>(as + r * 128 + ((g + r) & 7) * 16);
      }
      #pragma unroll
      for (int j = 0; j < 3; ++j) {
        int r = wn * 96 + j * 32 + l31;
        bb[j] = *reinterpret_cast<const short8*>(bs + r * 128 + ((g + r) & 7) * 16);
      }
      __builtin_amdgcn_s_setprio(1);
      #pragma unroll
      for (int i = 0; i < 2; ++i)
        #pragma unroll
        for (int j = 0; j < 3; ++j)
          acc[i][j] = __builtin_amdgcn_mfma_f32_32x32x16_bf16(a[i], bb[j], acc[i][j], 0, 0, 0);
      __builtin_amdgcn_s_setprio(0);
    }

    if (t < 10)       asm volatile("s_waitcnt vmcnt(4)" ::: "memory");
    else if (t == 10) asm volatile("s_waitcnt vmcnt(0)" ::: "memory");
    __builtin_amdgcn_s_barrier();
  }

  // epilogue: 32x32 C/D layout (m74/m101): col=lane&31,
  // row=(reg&3)+8*(reg>>2)+4*(lane>>5)
  const long long ob = (long long)b * 1572864;
  #pragma unroll
  for (int i = 0; i < 2; ++i)
    #pragma unroll
    for (int j = 0; j < 3; ++j)
      #pragma unroll
      for (int reg = 0; reg < 16; ++reg) {
        int row = m0 + wm * 64 + i * 32 + (reg & 3) + 8 * (reg >> 2) + 4 * lh;
        int col = n0 + wn * 96 + j * 32 + l31;
        C[ob + (long long)row * 768 + col] = acc[i][j][reg] * SCALE + rowv[b * 768 + col];
      }
}

extern "C" void kernel_launch(void* const* d_in, const int* in_sizes, int n_in,
                              void* d_out, int out_size, void* d_ws, size_t ws_size,
                              hipStream_t stream)
{
  const float* query = (const float*)d_in[0];
  const float* key   = (const float*)d_in[1];
  const float* prev  = (const float*)d_in[3];
  const int*   mask  = (const int*)d_in[4];
  const float* Wq    = (const float*)d_in[5];
  const float* bq    = (const float*)d_in[6];
  const float* Wk    = (const float*)d_in[7];
  const float* bk    = (const float*)d_in[8];
  const float* Wc    = (const float*)d_in[11];
  const float* bc    = (const float*)d_in[12];
  float* out = (float*)d_out;

  char* p = (char*)d_ws;
  size_t off = 0;
  auto alloc = [&](size_t bytes) {
    char* r = p + off;
    off += (bytes + 255) & ~(size_t)255;
    return r;
  };
  unsigned short* query_bf = (unsigned short*)alloc(12582912ull * 2);
  unsigned short* keyzT_bf = (unsigned short*)alloc(4718592ull * 2);
  unsigned short* WqT_bf   = (unsigned short*)alloc(589824ull * 2);
  unsigned short* WkT_bf   = (unsigned short*)alloc(589824ull * 2);
  unsigned short* prev_bf  = (unsigned short*)alloc(589824ull * 2);
  unsigned short* Wc2_bf   = (unsigned short*)alloc(589824ull * 2);
  float*          Mt_f     = (float*)alloc(589824ull * 4);
  unsigned short* Mt_bf    = (unsigned short*)alloc(589824ull * 2);
  unsigned short* W2_bf    = (unsigned short*)alloc(589824ull * 2);
  unsigned short* Tt_bf    = (unsigned short*)alloc(4718592ull * 2);
  unsigned short* Pt_bf    = (unsigned short*)alloc(4718592ull * 2);
  float*          s1f      = (float*)alloc(6144ull * 4);
  float*          sm0f     = (float*)alloc(6144ull * 4);
  float*          uv       = (float*)alloc(768ull * 4);
  float*          w3v      = (float*)alloc(768ull * 4);
  float*          rowv     = (float*)alloc(6144ull * 4);
  (void)ws_size; (void)in_sizes; (void)n_in; (void)out_size;

  // 1) all conversions/transposes (wide-store rewrite)
  k_prep_all<<<dim3(12, 12, 57), dim3(256), 0, stream>>>(
      Wq, Wk, key, mask, prev, Wc, query,
      WqT_bf, WkT_bf, keyzT_bf, prev_bf, Wc2_bf, query_bf);
  // 2) G1 + W2
  gemm_g1w2<<<dim3(12, 12, 2), dim3(256), 0, stream>>>(
      Wc2_bf, prev_bf, WqT_bf, WkT_bf, Wc, Mt_f, Mt_bf, W2_bf);
  // 3) u, w3, s1, sm0 (wide launch)
  k_sums<<<dim3(1920), dim3(256), 0, stream>>>(WqT_bf, WkT_bf, bk, bq, Mt_f, mask,
                                               uv, w3v, s1f, sm0f);
  // 4) G3': Tt[b] = NT(Mt, keyzT[b])
  g34_pipe<3><<<dim3(4, 8, 8), dim3(512), 0, stream>>>(
      Mt_bf, 0ll, keyzT_bf, 589824ll, Tt_bf,
      (const float*)nullptr, (const float*)nullptr);
  // 5) G4': Pt[b] = NT(Tt[b], W2) + s1[b][m]*u[n]
  g34_pipe<4><<<dim3(4, 8, 8), dim3(512), 0, stream>>>(
      Tt_bf, 589824ll, W2_bf, 0ll, Pt_bf, s1f, uv);
  // 6) row constants (wide launch)
  k_row<<<dim3(1536), dim3(256), 0, stream>>>(Tt_bf, w3v, s1f, sm0f, bq, bk, bc, rowv);
  // 7) G5 (32x32x16)
  g5_pipe<<<dim3(4, 8, 8), dim3(512), 0, stream>>>(query_bf, Pt_bf, out, rowv);
}